// Round 6
// baseline (2511.760 us; speedup 1.0000x reference)
//
#include <hip/hip_runtime.h>
#include <hip/hip_bf16.h>
#include <stdint.h>
#include <stddef.h>

#ifndef PARTITIONABLE
#define PARTITIONABLE 1
#endif

typedef __attribute__((ext_vector_type(8))) short short8;
typedef __attribute__((ext_vector_type(4))) short short4v;
typedef __attribute__((ext_vector_type(4))) float f32x4;

// ---------------- threefry2x32 (exact JAX) ----------------
__host__ __device__ __forceinline__ uint32_t rotl32(uint32_t x, int d){ return (x<<d)|(x>>(32-d)); }

__host__ __device__ __forceinline__ void tf4(uint32_t&x0, uint32_t&x1, int r0,int r1,int r2,int r3){
  x0+=x1; x1=rotl32(x1,r0); x1^=x0;
  x0+=x1; x1=rotl32(x1,r1); x1^=x0;
  x0+=x1; x1=rotl32(x1,r2); x1^=x0;
  x0+=x1; x1=rotl32(x1,r3); x1^=x0;
}
__host__ __device__ __forceinline__ void threefry2x32(uint32_t k0,uint32_t k1,uint32_t x0,uint32_t x1,
                                                      uint32_t&y0,uint32_t&y1){
  uint32_t ks2 = k0^k1^0x1BD11BDAu;
  x0+=k0; x1+=k1;
  tf4(x0,x1,13,15,26,6);  x0+=k1;  x1+=ks2+1u;
  tf4(x0,x1,17,29,16,24); x0+=ks2; x1+=k0+2u;
  tf4(x0,x1,13,15,26,6);  x0+=k0;  x1+=k1+3u;
  tf4(x0,x1,17,29,16,24); x0+=k1;  x1+=ks2+4u;
  tf4(x0,x1,13,15,26,6);  x0+=ks2; x1+=k0+5u;
  y0=x0; y1=x1;
}

__device__ __forceinline__ uint32_t random_bits32(uint32_t k0,uint32_t k1,uint32_t idx, uint32_t half){
#if PARTITIONABLE
  uint32_t y0,y1; threefry2x32(k0,k1, 0u, idx, y0,y1);
  (void)half;
  return y0 ^ y1;
#else
  uint32_t y0,y1;
  if (idx < half) { threefry2x32(k0,k1, idx, idx+half, y0,y1); return y0; }
  else            { threefry2x32(k0,k1, idx-half, idx, y0,y1); return y1; }
#endif
}

// ---------------- bf16 split helpers ----------------
__device__ __forceinline__ unsigned short bf16_rne(float x){
  unsigned u = __float_as_uint(x);
  unsigned r = (u + 0x7FFFu + ((u>>16)&1u)) >> 16;
  return (unsigned short)r;
}
__device__ __forceinline__ float bf16_tof(unsigned short h){
  return __uint_as_float(((unsigned)h)<<16);
}
__device__ __forceinline__ void split8(const float* src, short8& hi, short8& lo){
  #pragma unroll
  for (int e=0;e<8;e++){
    unsigned short h = bf16_rne(src[e]);
    hi[e] = (short)h;
    lo[e] = (short)bf16_rne(src[e] - bf16_tof(h));
  }
}
__device__ __forceinline__ void split4(const float* src, short4v& hi, short4v& lo){
  #pragma unroll
  for (int e=0;e<4;e++){
    unsigned short h = bf16_rne(src[e]);
    hi[e] = (short)h;
    lo[e] = (short)bf16_rne(src[e] - bf16_tof(h));
  }
}

// ---------------- async global->LDS (16B/lane) ----------------
__device__ __forceinline__ void gll16(const void* g, void* l){
  __builtin_amdgcn_global_load_lds(
      (const __attribute__((address_space(1))) unsigned int*)g,
      (__attribute__((address_space(3))) unsigned int*)l, 16, 0, 0);
}

// ---------------- Markidis split-2 core (bit-frozen vs rounds 4/5) ----------------
__device__ __forceinline__ void mk2_gemm(const float* __restrict__ A, int lda,
                                         const unsigned short* __restrict__ packB,
                                         int K, char* smem, f32x4 (&acc)[2][4]){
  const int tid=threadIdx.x, lane=tid&63, wv=tid>>6;
  const int wr=wv>>2, wc=wv&3;
  const int arow=tid>>3, aseg=tid&7, swA=(arow>>1)&3;
  unsigned short* Ahi=(unsigned short*)smem;
  unsigned short* Alo=(unsigned short*)(smem+8192);
  unsigned short* Bhi=(unsigned short*)(smem+16384);
  unsigned short* Blo=(unsigned short*)(smem+49152);
  const int NT=K/32;
  const int sA = arow*32 + ((aseg>>1)^swA)*8 + (aseg&1)*4;

  {
    float4 av = *(const float4*)(A + (size_t)arow*lda + aseg*4);
    const int seg = wv*2;
    #pragma unroll
    for(int q=0;q<2;q++){
      gll16(packB + (seg+q)*512 + lane*8,        (char*)Bhi + (seg+q)*1024);
      gll16(packB + 8192 + (seg+q)*512 + lane*8, (char*)Blo + (seg+q)*1024);
    }
    float af[4]={av.x,av.y,av.z,av.w}; short4v vh,vl; split4(af,vh,vl);
    *(short4v*)&Ahi[sA]=vh; *(short4v*)&Alo[sA]=vl;
  }
  __syncthreads();

  int cur=0;
  for(int t=0;t<NT;t++){
    const bool more = (t+1<NT);
    float4 anext;
    if(more){
      anext = *(const float4*)(A + (size_t)arow*lda + (t+1)*32 + aseg*4);
      const unsigned short* src = packB + (size_t)(t+1)*16384;
      const int seg = wv*2, nb = cur^1;
      #pragma unroll
      for(int q=0;q<2;q++){
        gll16(src + (seg+q)*512 + lane*8,        (char*)Bhi + nb*16384 + (seg+q)*1024);
        gll16(src + 8192 + (seg+q)*512 + lane*8, (char*)Blo + nb*16384 + (seg+q)*1024);
      }
    }
    short8 ah[2],al[2],bh[4],bl[4];
    const int kg=lane>>4;
    #pragma unroll
    for(int i=0;i<2;i++){
      const int r = wr*32 + i*16 + (lane&15);
      const int offA = cur*2048 + r*32 + ((kg ^ ((r>>1)&3))*8);
      ah[i]=*(const short8*)&Ahi[offA]; al[i]=*(const short8*)&Alo[offA];
    }
    #pragma unroll
    for(int j=0;j<4;j++){
      const int c = wc*64 + j*16 + (lane&15);
      const int offB = cur*8192 + c*32 + ((kg ^ ((c>>1)&3))*8);
      bh[j]=*(const short8*)&Bhi[offB]; bl[j]=*(const short8*)&Blo[offB];
    }
    #pragma unroll
    for(int i=0;i<2;i++)
      #pragma unroll
      for(int j=0;j<4;j++){
        acc[i][j]=__builtin_amdgcn_mfma_f32_16x16x32_bf16(ah[i],bh[j],acc[i][j],0,0,0);
        acc[i][j]=__builtin_amdgcn_mfma_f32_16x16x32_bf16(ah[i],bl[j],acc[i][j],0,0,0);
        acc[i][j]=__builtin_amdgcn_mfma_f32_16x16x32_bf16(al[i],bh[j],acc[i][j],0,0,0);
      }
    if(more){
      float af[4]={anext.x,anext.y,anext.z,anext.w}; short4v vh,vl; split4(af,vh,vl);
      const int nb=cur^1;
      *(short4v*)&Ahi[nb*2048 + sA]=vh; *(short4v*)&Alo[nb*2048 + sA]=vl;
    }
    __syncthreads();
    cur^=1;
  }
}

// ---------------- pack proj_w -> pre-split LDS-image layout (unchanged) ----------------
__global__ __launch_bounds__(256) void pack_w_kernel(const float* __restrict__ W,
                                                     unsigned short* __restrict__ pack){
  const int t = blockIdx.x>>2, s = blockIdx.x&3, c = threadIdx.x;
  const int g = s ^ ((c>>1)&3);
  const float* p = W + (size_t)(t*32 + g*8)*256 + c;
  float bf[8];
  #pragma unroll
  for(int e=0;e<8;e++) bf[e]=p[(size_t)e*256];
  short8 h,l; split8(bf,h,l);
  unsigned short* dst = pack + (size_t)t*16384 + c*32 + s*8;
  *(short8*)dst = h;
  *(short8*)(dst+8192) = l;
}

// ---------------- grid barrier among the 256 MLP blocks ----------------
__device__ __forceinline__ void gbar(int* ctr){
  __syncthreads();
  if (threadIdx.x==0){
    __threadfence();
    __hip_atomic_fetch_add(ctr, 1, __ATOMIC_RELEASE, __HIP_MEMORY_SCOPE_AGENT);
    while (__hip_atomic_load(ctr, __ATOMIC_ACQUIRE, __HIP_MEMORY_SCOPE_AGENT) < 256){
      __builtin_amdgcn_s_sleep(2);
    }
    __threadfence();
  }
  __syncthreads();
}

// ---------------- MLP phases (bit-exact replicas of the former kernels) ----------------
// fc0: jobs b*4..b*4+3 of the former 1024-block launch. No internal syncs.
__device__ void ph_fc0(const float* __restrict__ w0, const float* __restrict__ b0,
                       float* __restrict__ X0, int b, int tid){
  if (tid >= 256) return;
  #pragma unroll
  for (int q=0;q<4;q++){
    const int g = (b*4+q)*256 + tid;
    const int i = g >> 10, c = g & 1023;
    float acc = b0[c];
    #pragma unroll
    for (int j=0;j<8;j++) if ((i >> (7-j)) & 1) acc += w0[j*1024 + c];
    X0[g] = acc;
  }
}

// bn_relu over [256][1024], job b<16 (c0=b*64). Syncs executed by all 512 threads.
__device__ void ph_bn(char* smem, int b, const float* __restrict__ X,
                      const float* __restrict__ gma, const float* __restrict__ bta,
                      float* __restrict__ Y, int tid){
  float* red  = (float*)smem;          // [4][64]
  float* mcol = (float*)(smem+1024);   // [64]
  float* vcol = (float*)(smem+1280);   // [64]
  const int c0=b*64, cl=tid&63, rl=tid>>6;
  const int c=c0+cl;
  const bool w = (tid<256);
  float s=0.f;
  if (w){ for (int r=rl;r<256;r+=4) s += X[r*1024+c]; red[rl*64+cl]=s; }
  __syncthreads();
  if (w && rl==0) mcol[cl] = (red[0*64+cl]+red[1*64+cl]+red[2*64+cl]+red[3*64+cl])*(1.0f/256.0f);
  __syncthreads();
  float m = w ? mcol[cl] : 0.f;
  float s2=0.f;
  if (w){ for (int r=rl;r<256;r+=4){ float d=X[r*1024+c]-m; s2+=d*d; } red[rl*64+cl]=s2; }
  __syncthreads();
  if (w && rl==0) vcol[cl] = (red[0*64+cl]+red[1*64+cl]+red[2*64+cl]+red[3*64+cl])*(1.0f/256.0f);
  __syncthreads();
  if (w){
    float scale = gma[c]*rsqrtf(vcol[cl]+1e-5f);
    float sh = bta[c];
    for (int r=rl;r<256;r+=4){
      float v = (X[r*1024+c]-m)*scale + sh;
      Y[r*1024+c] = v>0.f ? v : 0.f;
    }
  }
}

// f32 GEMM tile phase (BM=32,BN=64,TM=2,TN=4,BK=16) — replica of gemm_f32<32,64,2,4>.
__device__ void ph_gemm(char* smem, int bx, int by,
                        const float* __restrict__ A, const float* __restrict__ B,
                        const float* __restrict__ bias, float* __restrict__ C,
                        int N, int K, int tid){
  constexpr int BM=32, BN=64, TM=2, TN=4, BK=16, PAD=4;
  float* As = (float*)smem;                       // [BK][BM+PAD]
  float* Bs = (float*)(smem + BK*(BM+PAD)*4);     // [BK][BN]
  const int bm=by*BM, bn=bx*BN;
  constexpr int NT=BN/TN;
  const int tc=tid%NT, tr=tid/NT;
  float acc[TM][TN];
  #pragma unroll
  for (int i=0;i<TM;i++)
    #pragma unroll
    for (int j=0;j<TN;j++) acc[i][j]=0.f;
  constexpr int AQ=BM*(BK/4), BQ=BK*(BN/4);
  for (int k0=0;k0<K;k0+=BK){
    if (tid<256){
      #pragma unroll
      for (int q=tid;q<AQ;q+=256){
        int m=q>>2, kq=q&3;
        const float4 v = *(const float4*)&A[(size_t)(bm+m)*K + k0 + kq*4];
        As[(kq*4+0)*(BM+PAD)+m]=v.x; As[(kq*4+1)*(BM+PAD)+m]=v.y;
        As[(kq*4+2)*(BM+PAD)+m]=v.z; As[(kq*4+3)*(BM+PAD)+m]=v.w;
      }
      #pragma unroll
      for (int q=tid;q<BQ;q+=256){
        int kk=q/(BN/4), nq=q%(BN/4);
        *(float4*)&Bs[kk*BN+nq*4] = *(const float4*)&B[(size_t)(k0+kk)*N + bn + nq*4];
      }
    }
    __syncthreads();
    if (tid<256){
      #pragma unroll
      for (int kk=0;kk<BK;kk++){
        float a[TM], bb[TN];
        #pragma unroll
        for (int i=0;i<TM;i++) a[i]=As[kk*(BM+PAD)+tr*TM+i];
        #pragma unroll
        for (int j=0;j<TN;j++) bb[j]=Bs[kk*BN+tc*TN+j];
        #pragma unroll
        for (int i=0;i<TM;i++)
          #pragma unroll
          for (int j=0;j<TN;j++)
            acc[i][j] += a[i]*bb[j];
      }
    }
    __syncthreads();
  }
  if (tid<256){
    #pragma unroll
    for (int i=0;i<TM;i++){
      const size_t row = (size_t)(bm + tr*TM + i);
      #pragma unroll
      for (int j=0;j<TN;j++){
        const size_t col = (size_t)(bn + tc*TN + j);
        float v = acc[i][j];
        if (bias) v += bias[col];
        C[row*(size_t)N + col] = v;
      }
    }
  }
}

// rownorm + packE, job n=b (one per block). One internal sync by all threads.
__device__ void ph_rnp(char* smem, int n, const float* __restrict__ X,
                       float* __restrict__ Y, unsigned short* __restrict__ pack, int tid){
  float* wsum = (float*)smem;  // [4]
  const int lane=tid&63, wv=tid>>6;
  float x=0.f;
  if (tid<256){
    x = X[(size_t)n*256 + tid];
    float v=x*x;
    #pragma unroll
    for (int o=32;o;o>>=1) v += __shfl_xor(v,o);
    if (lane==0) wsum[wv]=v;
  }
  __syncthreads();
  if (tid<256){
    float total = wsum[0]+wsum[1]+wsum[2]+wsum[3];
    float inv = 1.0f/(sqrtf(total)+1e-6f);
    float y = x*inv;
    Y[(size_t)n*256+tid] = y;
    unsigned short h = bf16_rne(y);
    unsigned short l = bf16_rne(y - bf16_tof(h));
    const int tt=tid>>5, kk=tid&31, g=kk>>3, e=kk&7, s=g^((n>>1)&3);
    unsigned short* d = pack + (size_t)tt*16384 + n*32 + s*8 + e;
    d[0]=h; d[8192]=l;
  }
}

// ---------------- proj tile (bit-frozen epilogue from round 5) ----------------
__device__ void proj_tile(const float* __restrict__ A, const unsigned short* __restrict__ packW,
                          const float* __restrict__ bias, float* __restrict__ Hn,
                          char* smem, int bm, int K){
  f32x4 acc[2][4];
  #pragma unroll
  for (int i=0;i<2;i++)
    #pragma unroll
    for (int j=0;j<4;j++) acc[i][j] = (f32x4){0.f,0.f,0.f,0.f};
  mk2_gemm(A + (size_t)bm*K, K, packW, K, smem, acc);

  const int tid = threadIdx.x, lane = tid&63, wv = tid>>6;
  const int wr = wv>>2, wc = wv&3;
  float* ns = (float*)smem;
  #pragma unroll
  for (int j=0;j<4;j++){
    const int c = wc*64 + j*16 + (lane&15);
    const float bb = bias[c];
    #pragma unroll
    for (int i=0;i<2;i++)
      #pragma unroll
      for (int reg=0;reg<4;reg++) acc[i][j][reg] += bb;
  }
  #pragma unroll
  for (int i=0;i<2;i++)
    #pragma unroll
    for (int reg=0;reg<4;reg++){
      float p = acc[i][0][reg]*acc[i][0][reg] + acc[i][1][reg]*acc[i][1][reg]
              + acc[i][2][reg]*acc[i][2][reg] + acc[i][3][reg]*acc[i][3][reg];
      #pragma unroll
      for (int o=1;o<16;o<<=1) p += __shfl_xor(p, o);
      if ((lane&15)==0) ns[wc*64 + wr*32 + i*16 + (lane>>4)*4 + reg] = p;
    }
  __syncthreads();
  #pragma unroll
  for (int i=0;i<2;i++){
    const int rl = wr*32 + i*16 + (lane>>4)*4;
    #pragma unroll
    for (int reg=0;reg<4;reg++){
      const int r = rl + reg;
      const float tot = ns[0*64+r]+ns[1*64+r]+ns[2*64+r]+ns[3*64+r];
      const float inv = 1.0f/(sqrtf(tot)+1e-6f);
      const size_t grow = (size_t)(bm + r);
      #pragma unroll
      for (int j=0;j<4;j++){
        const int c = wc*64 + j*16 + (lane&15);
        Hn[grow*256 + c] = acc[i][j][reg]*inv;
      }
    }
  }
}

// ---------------- fused kernel: blocks 0..255 = MLP pipeline, 256..511 = proj ----------------
__global__ __launch_bounds__(512,4) void coop_kernel(
    const float* __restrict__ h_in, const unsigned short* __restrict__ packW,
    const float* __restrict__ proj_b, float* __restrict__ Hn,
    const float* __restrict__ w0, const float* __restrict__ b0,
    const float* __restrict__ g0, const float* __restrict__ be0,
    const float* __restrict__ wm, const float* __restrict__ bm_a,
    const float* __restrict__ gm, const float* __restrict__ bem,
    const float* __restrict__ wL, const float* __restrict__ bL,
    const float* __restrict__ pinv_w, const float* __restrict__ pinv_b,
    float* __restrict__ X0b, float* __restrict__ X1b,
    float* __restrict__ embed, unsigned short* __restrict__ packE,
    float* __restrict__ Epp, int* __restrict__ bars){
  __shared__ char smem[81920];
  const int b = blockIdx.x;
  const int tid = threadIdx.x;

  if (b >= 256){
    const int tb = b - 256;
    proj_tile(h_in, packW, proj_b, Hn, smem, tb*64, 2048);
    __syncthreads();
    proj_tile(h_in, packW, proj_b, Hn, smem, (tb+256)*64, 2048);
    return;
  }

  // ---- MLP pipeline with grid barriers among blocks 0..255 ----
  ph_fc0(w0, b0, X0b, b, tid);
  gbar(&bars[0]);
  if (b < 16) ph_bn(smem, b, X0b, g0, be0, X1b, tid);
  gbar(&bars[1]);
  for (int l=0;l<4;l++){
    if (b < 128) ph_gemm(smem, b&15, b>>4, X1b, wm + (size_t)l*1048576, bm_a + l*1024, X0b, 1024, 1024, tid);
    gbar(&bars[2+2*l]);
    if (b < 16) ph_bn(smem, b, X0b, gm + l*1024, bem + l*1024, X1b, tid);
    gbar(&bars[3+2*l]);
  }
  if (b < 32) ph_gemm(smem, b&3, b>>2, X1b, wL, bL, X0b, 256, 1024, tid);
  gbar(&bars[10]);
  ph_rnp(smem, b, X0b, embed, packE, tid);
  gbar(&bars[11]);
  ph_gemm(smem, b&31, b>>5, embed, pinv_w, pinv_b, Epp, 2048, 256, tid);
}

// ---------------- sim GEMM + softmax + gumbel-argmax + outputs + q_inv, fused ----------------
__global__ __launch_bounds__(512) void sim_sample_kernel(
    const float* __restrict__ Hn, const unsigned short* __restrict__ packE,
    const float* __restrict__ embed, const float* __restrict__ temp,
    float* __restrict__ probs, float* __restrict__ codef,
    float* __restrict__ quant, float* __restrict__ norms,
    const float* __restrict__ Epp, const float* __restrict__ pinv_b,
    float* __restrict__ q_inv,
    uint32_t kc0, uint32_t kc1, uint32_t kp0, uint32_t kp1){
  __shared__ char smem[81920];
  f32x4 acc[2][4];
  #pragma unroll
  for (int i=0;i<2;i++)
    #pragma unroll
    for (int j=0;j<4;j++) acc[i][j] = (f32x4){0.f,0.f,0.f,0.f};
  const int bm = blockIdx.x * 64;
  mk2_gemm(Hn + (size_t)bm*256, 256, packE, 256, smem, acc);

  float* redf = (float*)smem;            // [4][64]
  int*   redi = (int*)(smem+1024);       // [4][64]
  float* smax = (float*)(smem+2048);     // [64]
  float* ssum = (float*)(smem+2304);     // [64]
  float* ssel = (float*)(smem+2560);     // [64]
  int*  scode = (int*)(smem+2816);       // [64]

  const int tid = threadIdx.x, lane = tid&63, wv = tid>>6;
  const int wr = wv>>2, wc = wv&3;
  const float tv = temp[0];
  const float alpha = 1.0f/(tv*tv);
  #pragma unroll
  for (int i=0;i<2;i++)
    #pragma unroll
    for (int j=0;j<4;j++)
      #pragma unroll
      for (int reg=0;reg<4;reg++){
        const float s = acc[i][j][reg];
        const float dist = -2.0f*(alpha-1.0f)*s - 2.0f*s;
        acc[i][j][reg] = -dist;
      }
  // row max
  #pragma unroll
  for (int i=0;i<2;i++)
    #pragma unroll
    for (int reg=0;reg<4;reg++){
      float m = fmaxf(fmaxf(acc[i][0][reg], acc[i][1][reg]),
                      fmaxf(acc[i][2][reg], acc[i][3][reg]));
      #pragma unroll
      for (int o=1;o<16;o<<=1) m = fmaxf(m, __shfl_xor(m, o));
      if ((lane&15)==0) redf[wc*64 + wr*32 + i*16 + (lane>>4)*4 + reg] = m;
    }
  __syncthreads();
  if (tid < 64)
    smax[tid] = fmaxf(fmaxf(redf[0*64+tid], redf[1*64+tid]), fmaxf(redf[2*64+tid], redf[3*64+tid]));
  __syncthreads();
  // exp-sum
  #pragma unroll
  for (int i=0;i<2;i++)
    #pragma unroll
    for (int reg=0;reg<4;reg++){
      const int r = wr*32 + i*16 + (lane>>4)*4 + reg;
      const float m = smax[r];
      float p = expf(acc[i][0][reg]-m) + expf(acc[i][1][reg]-m)
              + expf(acc[i][2][reg]-m) + expf(acc[i][3][reg]-m);
      #pragma unroll
      for (int o=1;o<16;o<<=1) p += __shfl_xor(p, o);
      if ((lane&15)==0) redf[wc*64 + r] = p;
    }
  __syncthreads();
  if (tid < 64){
    ssum[tid] = redf[0*64+tid]+redf[1*64+tid]+redf[2*64+tid]+redf[3*64+tid];
    const uint32_t pb = random_bits32(kp0,kp1,(uint32_t)(bm+tid), 16384u);
    const float pf = __uint_as_float((pb>>9) | 0x3f800000u) - 1.0f;
    ssel[tid] = (pf > 0.0f) ? 1.0f : 0.0f;
  }
  __syncthreads();
  // gumbel argmax (bit-frozen comparison order)
  #pragma unroll
  for (int i=0;i<2;i++)
    #pragma unroll
    for (int reg=0;reg<4;reg++){
      const int r = wr*32 + i*16 + (lane>>4)*4 + reg;
      const uint32_t grow = (uint32_t)(bm + r);
      float zb = -1e38f; int ib = 0x7fffffff;
      #pragma unroll
      for (int j=0;j<4;j++){
        const int c = wc*64 + j*16 + (lane&15);
        const uint32_t bits = random_bits32(kc0,kc1, grow*256u + (uint32_t)c, 4194304u);
        const float f = __uint_as_float((bits>>9) | 0x3f800000u) - 1.0f;
        const float TINY = 1.17549435082228751e-38f;
        const float u = fmaxf(TINY, f + TINY);
        const float g = -logf(-logf(u));
        const float z = acc[i][j][reg] + g;
        if (z > zb || (z == zb && c < ib)){ zb = z; ib = c; }
      }
      #pragma unroll
      for (int o=1;o<16;o<<=1){
        const float zo = __shfl_xor(zb, o); const int io = __shfl_xor(ib, o);
        if (zo > zb || (zo == zb && io < ib)){ zb = zo; ib = io; }
      }
      if ((lane&15)==0){ redf[wc*64 + r] = zb; redi[wc*64 + r] = ib; }
    }
  __syncthreads();
  if (tid < 64){
    float zb = redf[0*64+tid]; int ib = redi[0*64+tid];
    #pragma unroll
    for (int w=1; w<4; w++)
      if (redf[w*64+tid] > zb || (redf[w*64+tid] == zb && redi[w*64+tid] < ib)){
        zb = redf[w*64+tid]; ib = redi[w*64+tid];
      }
    scode[tid] = ib;
  }
  __syncthreads();
  // probs/quant + ||embed[code]-h|| partials
  #pragma unroll
  for (int i=0;i<2;i++)
    #pragma unroll
    for (int reg=0;reg<4;reg++){
      const int r = wr*32 + i*16 + (lane>>4)*4 + reg;
      const size_t grow = (size_t)(bm + r);
      const float m = smax[r], sum = ssum[r], sel = ssel[r];
      const int code = scode[r];
      float p2 = 0.f;
      #pragma unroll
      for (int j=0;j<4;j++){
        const int c = wc*64 + j*16 + (lane&15);
        const float e = expf(acc[i][j][reg] - m);
        probs[grow*256 + c] = (e/sum) * sel;
        const float ev = embed[(size_t)code*256 + c];
        quant[grow*256 + c] = ev * sel;
        const float d = ev - Hn[grow*256 + c];
        p2 += d*d;
      }
      #pragma unroll
      for (int o=1;o<16;o<<=1) p2 += __shfl_xor(p2, o);
      if ((lane&15)==0) redf[wc*64 + r] = p2;
    }
  __syncthreads();
  if (tid < 64){
    norms[bm+tid] = sqrtf(redf[0*64+tid]+redf[1*64+tid]+redf[2*64+tid]+redf[3*64+tid]);
    codef[bm+tid] = (float)scode[tid] * ssel[tid];
  }
  // q_inv rows: sel ? Epp[code] : pinv_b (wave wv owns rows wv*8..wv*8+7)
  #pragma unroll
  for (int rr=0; rr<8; rr++){
    const int r = wv*8 + rr;
    const int code = scode[r];
    const float sel = ssel[r];
    const float4* s4 = (const float4*)((sel != 0.0f) ? (Epp + (size_t)code*2048) : pinv_b);
    float4* dst = (float4*)(q_inv + (size_t)(bm + r)*2048);
    #pragma unroll
    for (int q=0;q<8;q++) dst[q*64 + lane] = s4[q*64 + lane];
  }
}

// ---------------- vq_loss = mean(norms) ----------------
__global__ __launch_bounds__(256) void loss_kernel(const float* __restrict__ norms,
                                                   float* __restrict__ outp){
  const int t = threadIdx.x;
  float s = 0.f;
  for (int i=t;i<32768;i+=256) s += norms[i];
  #pragma unroll
  for (int o=32;o;o>>=1) s += __shfl_xor(s,o);
  __shared__ float wred[4];
  if ((t&63)==0) wred[t>>6]=s;
  __syncthreads();
  if (t==0) outp[0] = (wred[0]+wred[1]+wred[2]+wred[3]) * (1.0f/32768.0f);
}

// ---------------- launch ----------------
extern "C" void kernel_launch(void* const* d_in, const int* in_sizes, int n_in,
                              void* d_out, int out_size, void* d_ws, size_t ws_size,
                              hipStream_t stream){
  const float* h_in  = (const float*)d_in[0];
  const float* temp  = (const float*)d_in[1];
  const float* proj_w= (const float*)d_in[2];
  const float* proj_b= (const float*)d_in[3];
  const float* pinv_w= (const float*)d_in[4];
  const float* pinv_b= (const float*)d_in[5];
  const float* w0 = (const float*)d_in[6];
  const float* b0 = (const float*)d_in[7];
  const float* g0 = (const float*)d_in[8];
  const float* be0= (const float*)d_in[9];
  const float* wm = (const float*)d_in[10];
  const float* bm = (const float*)d_in[11];
  const float* gm = (const float*)d_in[12];
  const float* bem= (const float*)d_in[13];
  const float* wL = (const float*)d_in[14];
  const float* bL = (const float*)d_in[15];

  float* out = (float*)d_out;
  float* q_inv  = out;                  // [32768,2048]
  float* o_code = out + 67108864;       // [32768]
  float* o_quant= out + 67141632;       // [32768,256]
  float* o_probs= out + 75530240;       // [32768,256]
  float* o_loss = out + 83918848;       // [1]

  // scratch in d_ws
  float* ws = (float*)d_ws;
  float* Hn     = ws + 0;               // [32768,256]
  float* X0b    = ws + 8388608;         // [256,1024]
  float* X1b    = ws + 8650752;         // [256,1024]
  float* embed  = ws + 8912896;         // [256,256]
  float* norms  = ws + 8978432;         // [32768]
  float* Epp    = ws + 9076736;         // [256,2048]
  unsigned short* packW = (unsigned short*)(ws + 9601024);   // 64 steps x 16384 shorts
  unsigned short* packE = (unsigned short*)(ws + 10125312);  // 8 steps x 16384 shorts
  int* bars = (int*)(ws + 11000000);    // 12 barrier counters

  uint32_t kc0,kc1,kp0,kp1;
#if PARTITIONABLE
  threefry2x32(0u,42u, 0u,0u, kc0,kc1);
  threefry2x32(0u,42u, 0u,1u, kp0,kp1);
#else
  { uint32_t a0,b0w,a1,b1w;
    threefry2x32(0u,42u, 0u,2u, a0,b0w);
    threefry2x32(0u,42u, 1u,3u, a1,b1w);
    kc0=a0; kc1=a1; kp0=b0w; kp1=b1w; }
#endif

  // zero barrier counters (captured op; re-zeroed on every replay)
  hipMemsetAsync(bars, 0, 12*sizeof(int), stream);

  // pre-split proj_w (proj path dependency — completed before coop launch)
  pack_w_kernel<<<256,256,0,stream>>>(proj_w, packW);

  // fused: proj(256 blocks, 2 tiles each) || MLP pipeline(256 blocks, 12 grid barriers)
  coop_kernel<<<512,512,0,stream>>>(h_in, packW, proj_b, Hn,
                                    w0,b0,g0,be0, wm,bm,gm,bem, wL,bL,
                                    pinv_w,pinv_b,
                                    X0b,X1b,embed,packE,Epp,bars);

  // sim + sample + all per-token outputs incl. q_inv
  sim_sample_kernel<<<512,512,0,stream>>>(Hn, packE, embed, temp,
                                          o_probs, o_code, o_quant, norms,
                                          Epp, pinv_b, q_inv,
                                          kc0,kc1,kp0,kp1);
  loss_kernel<<<1,256,0,stream>>>(norms, o_loss);
}

// Round 7
// 2294.282 us; speedup vs baseline: 1.0948x; 1.0948x over previous
//
#include <hip/hip_runtime.h>
#include <hip/hip_bf16.h>
#include <stdint.h>
#include <stddef.h>

#ifndef PARTITIONABLE
#define PARTITIONABLE 1
#endif

typedef __attribute__((ext_vector_type(8))) short short8;
typedef __attribute__((ext_vector_type(4))) short short4v;
typedef __attribute__((ext_vector_type(4))) float f32x4;

// ---------------- threefry2x32 (exact JAX) ----------------
__host__ __device__ __forceinline__ uint32_t rotl32(uint32_t x, int d){ return (x<<d)|(x>>(32-d)); }

__host__ __device__ __forceinline__ void tf4(uint32_t&x0, uint32_t&x1, int r0,int r1,int r2,int r3){
  x0+=x1; x1=rotl32(x1,r0); x1^=x0;
  x0+=x1; x1=rotl32(x1,r1); x1^=x0;
  x0+=x1; x1=rotl32(x1,r2); x1^=x0;
  x0+=x1; x1=rotl32(x1,r3); x1^=x0;
}
__host__ __device__ __forceinline__ void threefry2x32(uint32_t k0,uint32_t k1,uint32_t x0,uint32_t x1,
                                                      uint32_t&y0,uint32_t&y1){
  uint32_t ks2 = k0^k1^0x1BD11BDAu;
  x0+=k0; x1+=k1;
  tf4(x0,x1,13,15,26,6);  x0+=k1;  x1+=ks2+1u;
  tf4(x0,x1,17,29,16,24); x0+=ks2; x1+=k0+2u;
  tf4(x0,x1,13,15,26,6);  x0+=k0;  x1+=k1+3u;
  tf4(x0,x1,17,29,16,24); x0+=k1;  x1+=ks2+4u;
  tf4(x0,x1,13,15,26,6);  x0+=ks2; x1+=k0+5u;
  y0=x0; y1=x1;
}

__device__ __forceinline__ uint32_t random_bits32(uint32_t k0,uint32_t k1,uint32_t idx, uint32_t half){
#if PARTITIONABLE
  uint32_t y0,y1; threefry2x32(k0,k1, 0u, idx, y0,y1);
  (void)half;
  return y0 ^ y1;
#else
  uint32_t y0,y1;
  if (idx < half) { threefry2x32(k0,k1, idx, idx+half, y0,y1); return y0; }
  else            { threefry2x32(k0,k1, idx-half, idx, y0,y1); return y1; }
#endif
}

// ---------------- bf16 split helpers ----------------
__device__ __forceinline__ unsigned short bf16_rne(float x){
  unsigned u = __float_as_uint(x);
  unsigned r = (u + 0x7FFFu + ((u>>16)&1u)) >> 16;
  return (unsigned short)r;
}
__device__ __forceinline__ float bf16_tof(unsigned short h){
  return __uint_as_float(((unsigned)h)<<16);
}
__device__ __forceinline__ void split8(const float* src, short8& hi, short8& lo){
  #pragma unroll
  for (int e=0;e<8;e++){
    unsigned short h = bf16_rne(src[e]);
    hi[e] = (short)h;
    lo[e] = (short)bf16_rne(src[e] - bf16_tof(h));
  }
}
__device__ __forceinline__ void split4(const float* src, short4v& hi, short4v& lo){
  #pragma unroll
  for (int e=0;e<4;e++){
    unsigned short h = bf16_rne(src[e]);
    hi[e] = (short)h;
    lo[e] = (short)bf16_rne(src[e] - bf16_tof(h));
  }
}

// ---------------- async global->LDS (16B/lane) ----------------
__device__ __forceinline__ void gll16(const void* g, void* l){
  __builtin_amdgcn_global_load_lds(
      (const __attribute__((address_space(1))) unsigned int*)g,
      (__attribute__((address_space(3))) unsigned int*)l, 16, 0, 0);
}

// ---------------- Markidis split-2 core: single-buffer, 2 barriers/kstep, 40KB LDS ----------------
// LDS (shorts): Ahi[2048]@0, Alo[2048]@4096B, Bhi[8192]@8192B, Blo[8192]@24576B = 40960 B.
// B pre-packed (same image as rounds 5/6); per-(row,col) MFMA sequence bit-frozen.
__device__ __forceinline__ void mk1_gemm(const float* __restrict__ A, int lda,
                                         const unsigned short* __restrict__ packB,
                                         int K, char* smem, f32x4 (&acc)[2][4]){
  const int tid=threadIdx.x, lane=tid&63, wv=tid>>6;
  const int wr=wv>>2, wc=wv&3;
  const int arow=tid>>3, aseg=tid&7, swA=(arow>>1)&3;
  unsigned short* Ahi=(unsigned short*)smem;
  unsigned short* Alo=(unsigned short*)(smem+4096);
  unsigned short* Bhi=(unsigned short*)(smem+8192);
  unsigned short* Blo=(unsigned short*)(smem+24576);
  const int NT=K/32;
  const int sA = arow*32 + ((aseg>>1)^swA)*8 + (aseg&1)*4;
  const int seg = wv*2;

  float4 av = *(const float4*)(A + (size_t)arow*lda + aseg*4);
  for(int t=0;t<NT;t++){
    __syncthreads();                    // previous compute done; buffer free
    {
      float af[4]={av.x,av.y,av.z,av.w}; short4v vh,vl; split4(af,vh,vl);
      *(short4v*)&Ahi[sA]=vh; *(short4v*)&Alo[sA]=vl;
      const unsigned short* src = packB + (size_t)t*16384;
      #pragma unroll
      for(int q=0;q<2;q++){
        gll16(src + (seg+q)*512 + lane*8,        (char*)Bhi + (seg+q)*1024);
        gll16(src + 8192 + (seg+q)*512 + lane*8, (char*)Blo + (seg+q)*1024);
      }
      if (t+1<NT) av = *(const float4*)(A + (size_t)arow*lda + (t+1)*32 + aseg*4);
    }
    __syncthreads();                    // staging complete (vmcnt drained at barrier)
    short8 ah[2],al[2],bh[4],bl[4];
    const int kg=lane>>4;
    #pragma unroll
    for(int i=0;i<2;i++){
      const int r = wr*32 + i*16 + (lane&15);
      const int offA = r*32 + ((kg ^ ((r>>1)&3))*8);
      ah[i]=*(const short8*)&Ahi[offA]; al[i]=*(const short8*)&Alo[offA];
    }
    #pragma unroll
    for(int j=0;j<4;j++){
      const int c = wc*64 + j*16 + (lane&15);
      const int offB = c*32 + ((kg ^ ((c>>1)&3))*8);
      bh[j]=*(const short8*)&Bhi[offB]; bl[j]=*(const short8*)&Blo[offB];
    }
    #pragma unroll
    for(int i=0;i<2;i++)
      #pragma unroll
      for(int j=0;j<4;j++){
        acc[i][j]=__builtin_amdgcn_mfma_f32_16x16x32_bf16(ah[i],bh[j],acc[i][j],0,0,0);
        acc[i][j]=__builtin_amdgcn_mfma_f32_16x16x32_bf16(ah[i],bl[j],acc[i][j],0,0,0);
        acc[i][j]=__builtin_amdgcn_mfma_f32_16x16x32_bf16(al[i],bh[j],acc[i][j],0,0,0);
      }
  }
}

// ---------------- grid barrier among 256 coop blocks (grid==256 <= CU count: all resident) ----------------
__device__ __forceinline__ void gbar(int* ctr){
  __syncthreads();
  if (threadIdx.x==0){
    __threadfence();
    __hip_atomic_fetch_add(ctr, 1, __ATOMIC_RELEASE, __HIP_MEMORY_SCOPE_AGENT);
    while (__hip_atomic_load(ctr, __ATOMIC_ACQUIRE, __HIP_MEMORY_SCOPE_AGENT) < 256){
      __builtin_amdgcn_s_sleep(2);
    }
    __threadfence();
  }
  __syncthreads();
}

// ---------------- MLP phase device funcs (bit-exact replicas) ----------------
__device__ void ph_pack(const float* __restrict__ W, unsigned short* __restrict__ pack,
                        int b, int tid){
  if (tid >= 256) return;
  const int t = b>>2, s = b&3, c = tid;
  const int g = s ^ ((c>>1)&3);
  const float* p = W + (size_t)(t*32 + g*8)*256 + c;
  float bf[8];
  #pragma unroll
  for(int e=0;e<8;e++) bf[e]=p[(size_t)e*256];
  short8 h,l; split8(bf,h,l);
  unsigned short* dst = pack + (size_t)t*16384 + c*32 + s*8;
  *(short8*)dst = h;
  *(short8*)(dst+8192) = l;
}

__device__ void ph_fc0(const float* __restrict__ w0, const float* __restrict__ b0,
                       float* __restrict__ X0, int b, int tid){
  if (tid >= 256) return;
  #pragma unroll
  for (int q=0;q<4;q++){
    const int g = (b*4+q)*256 + tid;
    const int i = g >> 10, c = g & 1023;
    float acc = b0[c];
    #pragma unroll
    for (int j=0;j<8;j++) if ((i >> (7-j)) & 1) acc += w0[j*1024 + c];
    X0[g] = acc;
  }
}

__device__ void ph_bn(char* smem, int b, const float* __restrict__ X,
                      const float* __restrict__ gma, const float* __restrict__ bta,
                      float* __restrict__ Y, int tid){
  float* red  = (float*)smem;          // [4][64]
  float* mcol = (float*)(smem+1024);   // [64]
  float* vcol = (float*)(smem+1280);   // [64]
  const int c0=b*64, cl=tid&63, rl=tid>>6;
  const int c=c0+cl;
  const bool w = (tid<256);
  float s=0.f;
  if (w){ for (int r=rl;r<256;r+=4) s += X[r*1024+c]; red[rl*64+cl]=s; }
  __syncthreads();
  if (w && rl==0) mcol[cl] = (red[0*64+cl]+red[1*64+cl]+red[2*64+cl]+red[3*64+cl])*(1.0f/256.0f);
  __syncthreads();
  float m = w ? mcol[cl] : 0.f;
  float s2=0.f;
  if (w){ for (int r=rl;r<256;r+=4){ float d=X[r*1024+c]-m; s2+=d*d; } red[rl*64+cl]=s2; }
  __syncthreads();
  if (w && rl==0) vcol[cl] = (red[0*64+cl]+red[1*64+cl]+red[2*64+cl]+red[3*64+cl])*(1.0f/256.0f);
  __syncthreads();
  if (w){
    float scale = gma[c]*rsqrtf(vcol[cl]+1e-5f);
    float sh = bta[c];
    for (int r=rl;r<256;r+=4){
      float v = (X[r*1024+c]-m)*scale + sh;
      Y[r*1024+c] = v>0.f ? v : 0.f;
    }
  }
}

__device__ void ph_gemm(char* smem, int bx, int by,
                        const float* __restrict__ A, const float* __restrict__ B,
                        const float* __restrict__ bias, float* __restrict__ C,
                        int N, int K, int tid){
  constexpr int BM=32, BN=64, TM=2, TN=4, BK=16, PAD=4;
  float* As = (float*)smem;                       // [BK][BM+PAD]
  float* Bs = (float*)(smem + BK*(BM+PAD)*4);     // [BK][BN]
  const int bm=by*BM, bn=bx*BN;
  constexpr int NT=BN/TN;
  const int tc=tid%NT, tr=tid/NT;
  float acc[TM][TN];
  #pragma unroll
  for (int i=0;i<TM;i++)
    #pragma unroll
    for (int j=0;j<TN;j++) acc[i][j]=0.f;
  constexpr int AQ=BM*(BK/4), BQ=BK*(BN/4);
  for (int k0=0;k0<K;k0+=BK){
    if (tid<256){
      #pragma unroll
      for (int q=tid;q<AQ;q+=256){
        int m=q>>2, kq=q&3;
        const float4 v = *(const float4*)&A[(size_t)(bm+m)*K + k0 + kq*4];
        As[(kq*4+0)*(BM+PAD)+m]=v.x; As[(kq*4+1)*(BM+PAD)+m]=v.y;
        As[(kq*4+2)*(BM+PAD)+m]=v.z; As[(kq*4+3)*(BM+PAD)+m]=v.w;
      }
      #pragma unroll
      for (int q=tid;q<BQ;q+=256){
        int kk=q/(BN/4), nq=q%(BN/4);
        *(float4*)&Bs[kk*BN+nq*4] = *(const float4*)&B[(size_t)(k0+kk)*N + bn + nq*4];
      }
    }
    __syncthreads();
    if (tid<256){
      #pragma unroll
      for (int kk=0;kk<BK;kk++){
        float a[TM], bb[TN];
        #pragma unroll
        for (int i=0;i<TM;i++) a[i]=As[kk*(BM+PAD)+tr*TM+i];
        #pragma unroll
        for (int j=0;j<TN;j++) bb[j]=Bs[kk*BN+tc*TN+j];
        #pragma unroll
        for (int i=0;i<TM;i++)
          #pragma unroll
          for (int j=0;j<TN;j++)
            acc[i][j] += a[i]*bb[j];
      }
    }
    __syncthreads();
  }
  if (tid<256){
    #pragma unroll
    for (int i=0;i<TM;i++){
      const size_t row = (size_t)(bm + tr*TM + i);
      #pragma unroll
      for (int j=0;j<TN;j++){
        const size_t col = (size_t)(bn + tc*TN + j);
        float v = acc[i][j];
        if (bias) v += bias[col];
        C[row*(size_t)N + col] = v;
      }
    }
  }
}

__device__ void ph_rnp(char* smem, int n, const float* __restrict__ X,
                       float* __restrict__ Y, unsigned short* __restrict__ pack, int tid){
  float* wsum = (float*)smem;
  const int lane=tid&63, wv=tid>>6;
  float x=0.f;
  if (tid<256){
    x = X[(size_t)n*256 + tid];
    float v=x*x;
    #pragma unroll
    for (int o=32;o;o>>=1) v += __shfl_xor(v,o);
    if (lane==0) wsum[wv]=v;
  }
  __syncthreads();
  if (tid<256){
    float total = wsum[0]+wsum[1]+wsum[2]+wsum[3];
    float inv = 1.0f/(sqrtf(total)+1e-6f);
    float y = x*inv;
    Y[(size_t)n*256+tid] = y;
    unsigned short h = bf16_rne(y);
    unsigned short l = bf16_rne(y - bf16_tof(h));
    const int tt=tid>>5, kk=tid&31, g=kk>>3, e=kk&7, s=g^((n>>1)&3);
    unsigned short* d = pack + (size_t)tt*16384 + n*32 + s*8 + e;
    d[0]=h; d[8192]=l;
  }
}

// ---------------- MLP coop kernel: grid 256 (<= CU count -> all resident, barriers safe) ----------------
__global__ __launch_bounds__(512) void coop_mlp_kernel(
    const float* __restrict__ proj_w, unsigned short* __restrict__ packW,
    const float* __restrict__ w0, const float* __restrict__ b0,
    const float* __restrict__ g0, const float* __restrict__ be0,
    const float* __restrict__ wm, const float* __restrict__ bm_a,
    const float* __restrict__ gm, const float* __restrict__ bem,
    const float* __restrict__ wL, const float* __restrict__ bL,
    const float* __restrict__ pinv_w, const float* __restrict__ pinv_b,
    float* __restrict__ X0b, float* __restrict__ X1b,
    float* __restrict__ embed, unsigned short* __restrict__ packE,
    float* __restrict__ Epp, int* __restrict__ bars){
  __shared__ char smem[8192];
  const int b = blockIdx.x;
  const int tid = threadIdx.x;

  ph_pack(proj_w, packW, b, tid);           // phase 0: pack proj_w (no barrier needed here)
  ph_fc0(w0, b0, X0b, b, tid);
  gbar(&bars[0]);
  if (b < 16) ph_bn(smem, b, X0b, g0, be0, X1b, tid);
  gbar(&bars[1]);
  for (int l=0;l<4;l++){
    if (b < 128) ph_gemm(smem, b&15, b>>4, X1b, wm + (size_t)l*1048576, bm_a + l*1024, X0b, 1024, 1024, tid);
    gbar(&bars[2+2*l]);
    if (b < 16) ph_bn(smem, b, X0b, gm + l*1024, bem + l*1024, X1b, tid);
    gbar(&bars[3+2*l]);
  }
  if (b < 32) ph_gemm(smem, b&3, b>>2, X1b, wL, bL, X0b, 256, 1024, tid);
  gbar(&bars[10]);
  ph_rnp(smem, b, X0b, embed, packE, tid);
  gbar(&bars[11]);
  ph_gemm(smem, b&31, b>>5, embed, pinv_w, pinv_b, Epp, 2048, 256, tid);
}

// ---------------- proj + rownorm fused ----------------
__global__ __launch_bounds__(512) void proj_norm_kernel(
    const float* __restrict__ A, const unsigned short* __restrict__ packW,
    const float* __restrict__ bias, float* __restrict__ Hn, int K){
  __shared__ char smem[40960];
  f32x4 acc[2][4];
  #pragma unroll
  for (int i=0;i<2;i++)
    #pragma unroll
    for (int j=0;j<4;j++) acc[i][j] = (f32x4){0.f,0.f,0.f,0.f};
  const int bm = blockIdx.x * 64;
  mk1_gemm(A + (size_t)bm*K, K, packW, K, smem, acc);
  __syncthreads();                      // K-loop LDS reads done before epilogue aliasing

  const int tid = threadIdx.x, lane = tid&63, wv = tid>>6;
  const int wr = wv>>2, wc = wv&3;
  float* ns = (float*)smem;
  #pragma unroll
  for (int j=0;j<4;j++){
    const int c = wc*64 + j*16 + (lane&15);
    const float bb = bias[c];
    #pragma unroll
    for (int i=0;i<2;i++)
      #pragma unroll
      for (int reg=0;reg<4;reg++) acc[i][j][reg] += bb;
  }
  #pragma unroll
  for (int i=0;i<2;i++)
    #pragma unroll
    for (int reg=0;reg<4;reg++){
      float p = acc[i][0][reg]*acc[i][0][reg] + acc[i][1][reg]*acc[i][1][reg]
              + acc[i][2][reg]*acc[i][2][reg] + acc[i][3][reg]*acc[i][3][reg];
      #pragma unroll
      for (int o=1;o<16;o<<=1) p += __shfl_xor(p, o);
      if ((lane&15)==0) ns[wc*64 + wr*32 + i*16 + (lane>>4)*4 + reg] = p;
    }
  __syncthreads();
  #pragma unroll
  for (int i=0;i<2;i++){
    const int rl = wr*32 + i*16 + (lane>>4)*4;
    #pragma unroll
    for (int reg=0;reg<4;reg++){
      const int r = rl + reg;
      const float tot = ns[0*64+r]+ns[1*64+r]+ns[2*64+r]+ns[3*64+r];
      const float inv = 1.0f/(sqrtf(tot)+1e-6f);
      const size_t grow = (size_t)(bm + r);
      #pragma unroll
      for (int j=0;j<4;j++){
        const int c = wc*64 + j*16 + (lane&15);
        Hn[grow*256 + c] = acc[i][j][reg]*inv;
      }
    }
  }
}

// ---------------- sim GEMM + softmax + gumbel-argmax + outputs + q_inv, fused ----------------
__global__ __launch_bounds__(512) void sim_sample_kernel(
    const float* __restrict__ Hn, const unsigned short* __restrict__ packE,
    const float* __restrict__ embed, const float* __restrict__ temp,
    float* __restrict__ probs, float* __restrict__ codef,
    float* __restrict__ quant, float* __restrict__ norms,
    const float* __restrict__ Epp, const float* __restrict__ pinv_b,
    float* __restrict__ q_inv,
    uint32_t kc0, uint32_t kc1, uint32_t kp0, uint32_t kp1){
  __shared__ char smem[40960];
  f32x4 acc[2][4];
  #pragma unroll
  for (int i=0;i<2;i++)
    #pragma unroll
    for (int j=0;j<4;j++) acc[i][j] = (f32x4){0.f,0.f,0.f,0.f};
  const int bm = blockIdx.x * 64;
  mk1_gemm(Hn + (size_t)bm*256, 256, packE, 256, smem, acc);
  __syncthreads();                      // K-loop LDS reads done before epilogue aliasing

  float* redf = (float*)smem;            // [4][64]
  int*   redi = (int*)(smem+1024);       // [4][64]
  float* smax = (float*)(smem+2048);     // [64]
  float* ssum = (float*)(smem+2304);     // [64]
  float* ssel = (float*)(smem+2560);     // [64]
  int*  scode = (int*)(smem+2816);       // [64]

  const int tid = threadIdx.x, lane = tid&63, wv = tid>>6;
  const int wr = wv>>2, wc = wv&3;
  const float tv = temp[0];
  const float alpha = 1.0f/(tv*tv);
  #pragma unroll
  for (int i=0;i<2;i++)
    #pragma unroll
    for (int j=0;j<4;j++)
      #pragma unroll
      for (int reg=0;reg<4;reg++){
        const float s = acc[i][j][reg];
        const float dist = -2.0f*(alpha-1.0f)*s - 2.0f*s;
        acc[i][j][reg] = -dist;
      }
  // row max
  #pragma unroll
  for (int i=0;i<2;i++)
    #pragma unroll
    for (int reg=0;reg<4;reg++){
      float m = fmaxf(fmaxf(acc[i][0][reg], acc[i][1][reg]),
                      fmaxf(acc[i][2][reg], acc[i][3][reg]));
      #pragma unroll
      for (int o=1;o<16;o<<=1) m = fmaxf(m, __shfl_xor(m, o));
      if ((lane&15)==0) redf[wc*64 + wr*32 + i*16 + (lane>>4)*4 + reg] = m;
    }
  __syncthreads();
  if (tid < 64)
    smax[tid] = fmaxf(fmaxf(redf[0*64+tid], redf[1*64+tid]), fmaxf(redf[2*64+tid], redf[3*64+tid]));
  __syncthreads();
  // exp-sum
  #pragma unroll
  for (int i=0;i<2;i++)
    #pragma unroll
    for (int reg=0;reg<4;reg++){
      const int r = wr*32 + i*16 + (lane>>4)*4 + reg;
      const float m = smax[r];
      float p = expf(acc[i][0][reg]-m) + expf(acc[i][1][reg]-m)
              + expf(acc[i][2][reg]-m) + expf(acc[i][3][reg]-m);
      #pragma unroll
      for (int o=1;o<16;o<<=1) p += __shfl_xor(p, o);
      if ((lane&15)==0) redf[wc*64 + r] = p;
    }
  __syncthreads();
  if (tid < 64){
    ssum[tid] = redf[0*64+tid]+redf[1*64+tid]+redf[2*64+tid]+redf[3*64+tid];
    const uint32_t pb = random_bits32(kp0,kp1,(uint32_t)(bm+tid), 16384u);
    const float pf = __uint_as_float((pb>>9) | 0x3f800000u) - 1.0f;
    ssel[tid] = (pf > 0.0f) ? 1.0f : 0.0f;
  }
  __syncthreads();
  // gumbel argmax (bit-frozen comparison order)
  #pragma unroll
  for (int i=0;i<2;i++)
    #pragma unroll
    for (int reg=0;reg<4;reg++){
      const int r = wr*32 + i*16 + (lane>>4)*4 + reg;
      const uint32_t grow = (uint32_t)(bm + r);
      float zb = -1e38f; int ib = 0x7fffffff;
      #pragma unroll
      for (int j=0;j<4;j++){
        const int c = wc*64 + j*16 + (lane&15);
        const uint32_t bits = random_bits32(kc0,kc1, grow*256u + (uint32_t)c, 4194304u);
        const float f = __uint_as_float((bits>>9) | 0x3f800000u) - 1.0f;
        const float TINY = 1.17549435082228751e-38f;
        const float u = fmaxf(TINY, f + TINY);
        const float g = -logf(-logf(u));
        const float z = acc[i][j][reg] + g;
        if (z > zb || (z == zb && c < ib)){ zb = z; ib = c; }
      }
      #pragma unroll
      for (int o=1;o<16;o<<=1){
        const float zo = __shfl_xor(zb, o); const int io = __shfl_xor(ib, o);
        if (zo > zb || (zo == zb && io < ib)){ zb = zo; ib = io; }
      }
      if ((lane&15)==0){ redf[wc*64 + r] = zb; redi[wc*64 + r] = ib; }
    }
  __syncthreads();
  if (tid < 64){
    float zb = redf[0*64+tid]; int ib = redi[0*64+tid];
    #pragma unroll
    for (int w=1; w<4; w++)
      if (redf[w*64+tid] > zb || (redf[w*64+tid] == zb && redi[w*64+tid] < ib)){
        zb = redf[w*64+tid]; ib = redi[w*64+tid];
      }
    scode[tid] = ib;
  }
  __syncthreads();
  // probs/quant + ||embed[code]-h|| partials
  #pragma unroll
  for (int i=0;i<2;i++)
    #pragma unroll
    for (int reg=0;reg<4;reg++){
      const int r = wr*32 + i*16 + (lane>>4)*4 + reg;
      const size_t grow = (size_t)(bm + r);
      const float m = smax[r], sum = ssum[r], sel = ssel[r];
      const int code = scode[r];
      float p2 = 0.f;
      #pragma unroll
      for (int j=0;j<4;j++){
        const int c = wc*64 + j*16 + (lane&15);
        const float e = expf(acc[i][j][reg] - m);
        probs[grow*256 + c] = (e/sum) * sel;
        const float ev = embed[(size_t)code*256 + c];
        quant[grow*256 + c] = ev * sel;
        const float d = ev - Hn[grow*256 + c];
        p2 += d*d;
      }
      #pragma unroll
      for (int o=1;o<16;o<<=1) p2 += __shfl_xor(p2, o);
      if ((lane&15)==0) redf[wc*64 + r] = p2;
    }
  __syncthreads();
  if (tid < 64){
    norms[bm+tid] = sqrtf(redf[0*64+tid]+redf[1*64+tid]+redf[2*64+tid]+redf[3*64+tid]);
    codef[bm+tid] = (float)scode[tid] * ssel[tid];
  }
  // q_inv rows: sel ? Epp[code] : pinv_b (wave wv owns rows wv*8..wv*8+7)
  #pragma unroll
  for (int rr=0; rr<8; rr++){
    const int r = wv*8 + rr;
    const int code = scode[r];
    const float sel = ssel[r];
    const float4* s4 = (const float4*)((sel != 0.0f) ? (Epp + (size_t)code*2048) : pinv_b);
    float4* dst = (float4*)(q_inv + (size_t)(bm + r)*2048);
    #pragma unroll
    for (int q=0;q<8;q++) dst[q*64 + lane] = s4[q*64 + lane];
  }
}

// ---------------- vq_loss = mean(norms) ----------------
__global__ __launch_bounds__(256) void loss_kernel(const float* __restrict__ norms,
                                                   float* __restrict__ outp){
  const int t = threadIdx.x;
  float s = 0.f;
  for (int i=t;i<32768;i+=256) s += norms[i];
  #pragma unroll
  for (int o=32;o;o>>=1) s += __shfl_xor(s,o);
  __shared__ float wred[4];
  if ((t&63)==0) wred[t>>6]=s;
  __syncthreads();
  if (t==0) outp[0] = (wred[0]+wred[1]+wred[2]+wred[3]) * (1.0f/32768.0f);
}

// ---------------- launch ----------------
extern "C" void kernel_launch(void* const* d_in, const int* in_sizes, int n_in,
                              void* d_out, int out_size, void* d_ws, size_t ws_size,
                              hipStream_t stream){
  const float* h_in  = (const float*)d_in[0];
  const float* temp  = (const float*)d_in[1];
  const float* proj_w= (const float*)d_in[2];
  const float* proj_b= (const float*)d_in[3];
  const float* pinv_w= (const float*)d_in[4];
  const float* pinv_b= (const float*)d_in[5];
  const float* w0 = (const float*)d_in[6];
  const float* b0 = (const float*)d_in[7];
  const float* g0 = (const float*)d_in[8];
  const float* be0= (const float*)d_in[9];
  const float* wm = (const float*)d_in[10];
  const float* bm = (const float*)d_in[11];
  const float* gm = (const float*)d_in[12];
  const float* bem= (const float*)d_in[13];
  const float* wL = (const float*)d_in[14];
  const float* bL = (const float*)d_in[15];

  float* out = (float*)d_out;
  float* q_inv  = out;                  // [32768,2048]
  float* o_code = out + 67108864;       // [32768]
  float* o_quant= out + 67141632;       // [32768,256]
  float* o_probs= out + 75530240;       // [32768,256]
  float* o_loss = out + 83918848;       // [1]

  // scratch in d_ws
  float* ws = (float*)d_ws;
  float* Hn     = ws + 0;               // [32768,256]
  float* X0b    = ws + 8388608;         // [256,1024]
  float* X1b    = ws + 8650752;         // [256,1024]
  float* embed  = ws + 8912896;         // [256,256]
  float* norms  = ws + 8978432;         // [32768]
  float* Epp    = ws + 9076736;         // [256,2048]
  unsigned short* packW = (unsigned short*)(ws + 9601024);   // 64 steps x 16384 shorts
  unsigned short* packE = (unsigned short*)(ws + 10125312);  // 8 steps x 16384 shorts
  int* bars = (int*)(ws + 11000000);    // 12 barrier counters

  uint32_t kc0,kc1,kp0,kp1;
#if PARTITIONABLE
  threefry2x32(0u,42u, 0u,0u, kc0,kc1);
  threefry2x32(0u,42u, 0u,1u, kp0,kp1);
#else
  { uint32_t a0,b0w,a1,b1w;
    threefry2x32(0u,42u, 0u,2u, a0,b0w);
    threefry2x32(0u,42u, 1u,3u, a1,b1w);
    kc0=a0; kc1=a1; kp0=b0w; kp1=b1w; }
#endif

  // zero barrier counters (captured op; re-zeroed on every replay)
  hipMemsetAsync(bars, 0, 12*sizeof(int), stream);

  // pack proj_w + entire codebook MLP + packE + Epp, one safe coop launch (grid 256)
  coop_mlp_kernel<<<256,512,0,stream>>>(proj_w, packW,
                                        w0,b0,g0,be0, wm,bm,gm,bem, wL,bL,
                                        pinv_w,pinv_b,
                                        X0b,X1b,embed,packE,Epp,bars);

  // fused proj+normalize (512 blocks, 40KB LDS -> 2 blocks/CU)
  proj_norm_kernel<<<512,512,0,stream>>>(h_in, packW, proj_b, Hn, 2048);

  // sim + sample + all per-token outputs incl. q_inv
  sim_sample_kernel<<<512,512,0,stream>>>(Hn, packE, embed, temp,
                                          o_probs, o_code, o_quant, norms,
                                          Epp, pinv_b, q_inv,
                                          kc0,kc1,kp0,kp1);
  loss_kernel<<<1,256,0,stream>>>(norms, o_loss);
}

// Round 8
// 767.337 us; speedup vs baseline: 3.2733x; 2.9899x over previous
//
#include <hip/hip_runtime.h>
#include <hip/hip_bf16.h>
#include <stdint.h>
#include <stddef.h>

#ifndef PARTITIONABLE
#define PARTITIONABLE 1
#endif

typedef __attribute__((ext_vector_type(8))) short short8;
typedef __attribute__((ext_vector_type(4))) short short4v;
typedef __attribute__((ext_vector_type(4))) float f32x4;

// ---------------- threefry2x32 (exact JAX) ----------------
__host__ __device__ __forceinline__ uint32_t rotl32(uint32_t x, int d){ return (x<<d)|(x>>(32-d)); }

__host__ __device__ __forceinline__ void tf4(uint32_t&x0, uint32_t&x1, int r0,int r1,int r2,int r3){
  x0+=x1; x1=rotl32(x1,r0); x1^=x0;
  x0+=x1; x1=rotl32(x1,r1); x1^=x0;
  x0+=x1; x1=rotl32(x1,r2); x1^=x0;
  x0+=x1; x1=rotl32(x1,r3); x1^=x0;
}
__host__ __device__ __forceinline__ void threefry2x32(uint32_t k0,uint32_t k1,uint32_t x0,uint32_t x1,
                                                      uint32_t&y0,uint32_t&y1){
  uint32_t ks2 = k0^k1^0x1BD11BDAu;
  x0+=k0; x1+=k1;
  tf4(x0,x1,13,15,26,6);  x0+=k1;  x1+=ks2+1u;
  tf4(x0,x1,17,29,16,24); x0+=ks2; x1+=k0+2u;
  tf4(x0,x1,13,15,26,6);  x0+=k0;  x1+=k1+3u;
  tf4(x0,x1,17,29,16,24); x0+=k1;  x1+=ks2+4u;
  tf4(x0,x1,13,15,26,6);  x0+=ks2; x1+=k0+5u;
  y0=x0; y1=x1;
}

__device__ __forceinline__ uint32_t random_bits32(uint32_t k0,uint32_t k1,uint32_t idx, uint32_t half){
#if PARTITIONABLE
  uint32_t y0,y1; threefry2x32(k0,k1, 0u, idx, y0,y1);
  (void)half;
  return y0 ^ y1;
#else
  uint32_t y0,y1;
  if (idx < half) { threefry2x32(k0,k1, idx, idx+half, y0,y1); return y0; }
  else            { threefry2x32(k0,k1, idx-half, idx, y0,y1); return y1; }
#endif
}

// ---------------- bf16 split helpers ----------------
__device__ __forceinline__ unsigned short bf16_rne(float x){
  unsigned u = __float_as_uint(x);
  unsigned r = (u + 0x7FFFu + ((u>>16)&1u)) >> 16;
  return (unsigned short)r;
}
__device__ __forceinline__ float bf16_tof(unsigned short h){
  return __uint_as_float(((unsigned)h)<<16);
}
__device__ __forceinline__ void split8(const float* src, short8& hi, short8& lo){
  #pragma unroll
  for (int e=0;e<8;e++){
    unsigned short h = bf16_rne(src[e]);
    hi[e] = (short)h;
    lo[e] = (short)bf16_rne(src[e] - bf16_tof(h));
  }
}
__device__ __forceinline__ void split4(const float* src, short4v& hi, short4v& lo){
  #pragma unroll
  for (int e=0;e<4;e++){
    unsigned short h = bf16_rne(src[e]);
    hi[e] = (short)h;
    lo[e] = (short)bf16_rne(src[e] - bf16_tof(h));
  }
}

// ---------------- async global->LDS (16B/lane) ----------------
__device__ __forceinline__ void gll16(const void* g, void* l){
  __builtin_amdgcn_global_load_lds(
      (const __attribute__((address_space(1))) unsigned int*)g,
      (__attribute__((address_space(3))) unsigned int*)l, 16, 0, 0);
}

// ---------------- Markidis split-2 core: single-buffer, 2 barriers/kstep, 40KB LDS ----------------
// LDS (shorts): Ahi[2048]@0, Alo[2048]@4096B, Bhi[8192]@8192B, Blo[8192]@24576B = 40960 B.
// B pre-packed; per-(row,col) MFMA sequence bit-frozen vs rounds 4-7.
__device__ __forceinline__ void mk1_gemm(const float* __restrict__ A, int lda,
                                         const unsigned short* __restrict__ packB,
                                         int K, char* smem, f32x4 (&acc)[2][4]){
  const int tid=threadIdx.x, lane=tid&63, wv=tid>>6;
  const int wr=wv>>2, wc=wv&3;
  const int arow=tid>>3, aseg=tid&7, swA=(arow>>1)&3;
  unsigned short* Ahi=(unsigned short*)smem;
  unsigned short* Alo=(unsigned short*)(smem+4096);
  unsigned short* Bhi=(unsigned short*)(smem+8192);
  unsigned short* Blo=(unsigned short*)(smem+24576);
  const int NT=K/32;
  const int sA = arow*32 + ((aseg>>1)^swA)*8 + (aseg&1)*4;
  const int seg = wv*2;

  float4 av = *(const float4*)(A + (size_t)arow*lda + aseg*4);
  for(int t=0;t<NT;t++){
    __syncthreads();                    // previous compute done; buffer free
    {
      float af[4]={av.x,av.y,av.z,av.w}; short4v vh,vl; split4(af,vh,vl);
      *(short4v*)&Ahi[sA]=vh; *(short4v*)&Alo[sA]=vl;
      const unsigned short* src = packB + (size_t)t*16384;
      #pragma unroll
      for(int q=0;q<2;q++){
        gll16(src + (seg+q)*512 + lane*8,        (char*)Bhi + (seg+q)*1024);
        gll16(src + 8192 + (seg+q)*512 + lane*8, (char*)Blo + (seg+q)*1024);
      }
      if (t+1<NT) av = *(const float4*)(A + (size_t)arow*lda + (t+1)*32 + aseg*4);
    }
    __syncthreads();                    // staging complete (vmcnt drained at barrier)
    short8 ah[2],al[2],bh[4],bl[4];
    const int kg=lane>>4;
    #pragma unroll
    for(int i=0;i<2;i++){
      const int r = wr*32 + i*16 + (lane&15);
      const int offA = r*32 + ((kg ^ ((r>>1)&3))*8);
      ah[i]=*(const short8*)&Ahi[offA]; al[i]=*(const short8*)&Alo[offA];
    }
    #pragma unroll
    for(int j=0;j<4;j++){
      const int c = wc*64 + j*16 + (lane&15);
      const int offB = c*32 + ((kg ^ ((c>>1)&3))*8);
      bh[j]=*(const short8*)&Bhi[offB]; bl[j]=*(const short8*)&Blo[offB];
    }
    #pragma unroll
    for(int i=0;i<2;i++)
      #pragma unroll
      for(int j=0;j<4;j++){
        acc[i][j]=__builtin_amdgcn_mfma_f32_16x16x32_bf16(ah[i],bh[j],acc[i][j],0,0,0);
        acc[i][j]=__builtin_amdgcn_mfma_f32_16x16x32_bf16(ah[i],bl[j],acc[i][j],0,0,0);
        acc[i][j]=__builtin_amdgcn_mfma_f32_16x16x32_bf16(al[i],bh[j],acc[i][j],0,0,0);
      }
  }
}

// ---------------- pack proj_w -> pre-split LDS-image layout ----------------
__global__ __launch_bounds__(256) void pack_w_kernel(const float* __restrict__ W,
                                                     unsigned short* __restrict__ pack){
  const int t = blockIdx.x>>2, s = blockIdx.x&3, c = threadIdx.x;
  const int g = s ^ ((c>>1)&3);
  const float* p = W + (size_t)(t*32 + g*8)*256 + c;
  float bf[8];
  #pragma unroll
  for(int e=0;e<8;e++) bf[e]=p[(size_t)e*256];
  short8 h,l; split8(bf,h,l);
  unsigned short* dst = pack + (size_t)t*16384 + c*32 + s*8;
  *(short8*)dst = h;
  *(short8*)(dst+8192) = l;
}

// ---------------- f32 vector GEMM (codebook MLP; k-sequential, bit-stable) ----------------
template<int BM, int BN, int TM, int TN>
__global__ __launch_bounds__(256) void gemm_f32(
    const float* __restrict__ A, const float* __restrict__ B,
    const float* __restrict__ bias, float* __restrict__ C,
    int M, int N, int K){
  constexpr int BK = 16;
  constexpr int PAD = 4;
  __shared__ float As[BK][BM+PAD];
  __shared__ float Bs[BK][BN];
  const int tid = threadIdx.x;
  const int bm = blockIdx.y*BM, bn = blockIdx.x*BN;
  constexpr int NT = BN/TN;
  const int tc = tid % NT, tr = tid / NT;
  float acc[TM][TN];
  #pragma unroll
  for (int i=0;i<TM;i++)
    #pragma unroll
    for(int j=0;j<TN;j++) acc[i][j]=0.f;

  constexpr int AQ = BM*(BK/4);
  constexpr int BQ = BK*(BN/4);

  for (int k0=0;k0<K;k0+=BK){
    #pragma unroll
    for (int q=tid; q<AQ; q+=256){
      int m = q >> 2, kq = q & 3;
      const float4 v = *(const float4*)&A[(size_t)(bm+m)*K + k0 + kq*4];
      As[kq*4+0][m]=v.x; As[kq*4+1][m]=v.y; As[kq*4+2][m]=v.z; As[kq*4+3][m]=v.w;
    }
    #pragma unroll
    for (int q=tid; q<BQ; q+=256){
      int kk = q / (BN/4), nq = q % (BN/4);
      *(float4*)&Bs[kk][nq*4] = *(const float4*)&B[(size_t)(k0+kk)*N + bn + nq*4];
    }
    __syncthreads();
    #pragma unroll
    for (int kk=0;kk<BK;kk++){
      float a[TM], b[TN];
      #pragma unroll
      for (int i=0;i<TM;i++) a[i]=As[kk][tr*TM+i];
      #pragma unroll
      for (int j=0;j<TN;j++) b[j]=Bs[kk][tc*TN+j];
      #pragma unroll
      for (int i=0;i<TM;i++)
        #pragma unroll
        for (int j=0;j<TN;j++)
          acc[i][j] += a[i]*b[j];
    }
    __syncthreads();
  }
  #pragma unroll
  for (int i=0;i<TM;i++){
    const size_t row = (size_t)(bm + tr*TM + i);
    #pragma unroll
    for (int j=0;j<TN;j++){
      const size_t col = (size_t)(bn + tc*TN + j);
      float v = acc[i][j];
      if (bias) v += bias[col];
      C[row*(size_t)N + col] = v;
    }
  }
}

// ---------------- codebook first layer ----------------
__global__ __launch_bounds__(256) void cb_fc0_kernel(const float* __restrict__ w0,
                                                     const float* __restrict__ b0,
                                                     float* __restrict__ X0){
  int g = blockIdx.x*256 + threadIdx.x;
  int i = g >> 10, c = g & 1023;
  float acc = b0[c];
  #pragma unroll
  for (int j=0;j<8;j++) if ((i >> (7-j)) & 1) acc += w0[j*1024 + c];
  X0[g] = acc;
}

// ---------------- BN (batch stats over 256 rows) + ReLU ----------------
__global__ __launch_bounds__(256) void bn_relu_kernel(const float* __restrict__ X,
                                                      const float* __restrict__ gma,
                                                      const float* __restrict__ bta,
                                                      float* __restrict__ Y, int C){
  const int c0 = blockIdx.x*64;
  const int t = threadIdx.x;
  const int cl = t & 63, rl = t >> 6;
  const int c = c0 + cl;
  __shared__ float red[4][64];
  __shared__ float mcol[64], vcol[64];

  float s = 0.f;
  for (int r = rl; r < 256; r += 4) s += X[r*C + c];
  red[rl][cl] = s; __syncthreads();
  if (rl==0) mcol[cl] = (red[0][cl]+red[1][cl]+red[2][cl]+red[3][cl]) * (1.0f/256.0f);
  __syncthreads();
  float m = mcol[cl];
  float s2 = 0.f;
  for (int r = rl; r < 256; r += 4){ float d = X[r*C+c]-m; s2 += d*d; }
  red[rl][cl] = s2; __syncthreads();
  if (rl==0) vcol[cl] = (red[0][cl]+red[1][cl]+red[2][cl]+red[3][cl]) * (1.0f/256.0f);
  __syncthreads();
  float scale = gma[c] * rsqrtf(vcol[cl] + 1e-5f);
  float sh = bta[c];
  for (int r = rl; r < 256; r += 4){
    float v = (X[r*C+c]-m)*scale + sh;
    Y[r*C+c] = v > 0.f ? v : 0.f;
  }
}

// ---------------- row L2-normalize for embed + pack for sim B ----------------
__global__ __launch_bounds__(256) void rownorm_pack_kernel(const float* __restrict__ X,
                                                           float* __restrict__ Y,
                                                           unsigned short* __restrict__ pack){
  const int n = blockIdx.x, t = threadIdx.x;
  const int lane = t & 63, wv = t >> 6;
  float x = X[(size_t)n*256 + t];
  float v = x*x;
  #pragma unroll
  for (int o=32;o;o>>=1) v += __shfl_xor(v,o);
  __shared__ float wsum[4];
  if (lane==0) wsum[wv]=v;
  __syncthreads();
  float total = wsum[0]+wsum[1]+wsum[2]+wsum[3];
  float inv = 1.0f/(sqrtf(total)+1e-6f);
  float y = x*inv;
  Y[(size_t)n*256+t] = y;
  unsigned short h = bf16_rne(y);
  unsigned short l = bf16_rne(y - bf16_tof(h));
  const int tt=t>>5, kk=t&31, g=kk>>3, e=kk&7, s=g^((n>>1)&3);
  unsigned short* d = pack + (size_t)tt*16384 + n*32 + s*8 + e;
  d[0] = h; d[8192] = l;
}

// ---------------- proj + rownorm fused ----------------
__global__ __launch_bounds__(512) void proj_norm_kernel(
    const float* __restrict__ A, const unsigned short* __restrict__ packW,
    const float* __restrict__ bias, float* __restrict__ Hn, int K){
  __shared__ char smem[40960];
  f32x4 acc[2][4];
  #pragma unroll
  for (int i=0;i<2;i++)
    #pragma unroll
    for (int j=0;j<4;j++) acc[i][j] = (f32x4){0.f,0.f,0.f,0.f};
  const int bm = blockIdx.x * 64;
  mk1_gemm(A + (size_t)bm*K, K, packW, K, smem, acc);
  __syncthreads();                      // K-loop LDS reads done before epilogue aliasing

  const int tid = threadIdx.x, lane = tid&63, wv = tid>>6;
  const int wr = wv>>2, wc = wv&3;
  float* ns = (float*)smem;
  #pragma unroll
  for (int j=0;j<4;j++){
    const int c = wc*64 + j*16 + (lane&15);
    const float bb = bias[c];
    #pragma unroll
    for (int i=0;i<2;i++)
      #pragma unroll
      for (int reg=0;reg<4;reg++) acc[i][j][reg] += bb;
  }
  #pragma unroll
  for (int i=0;i<2;i++)
    #pragma unroll
    for (int reg=0;reg<4;reg++){
      float p = acc[i][0][reg]*acc[i][0][reg] + acc[i][1][reg]*acc[i][1][reg]
              + acc[i][2][reg]*acc[i][2][reg] + acc[i][3][reg]*acc[i][3][reg];
      #pragma unroll
      for (int o=1;o<16;o<<=1) p += __shfl_xor(p, o);
      if ((lane&15)==0) ns[wc*64 + wr*32 + i*16 + (lane>>4)*4 + reg] = p;
    }
  __syncthreads();
  #pragma unroll
  for (int i=0;i<2;i++){
    const int rl = wr*32 + i*16 + (lane>>4)*4;
    #pragma unroll
    for (int reg=0;reg<4;reg++){
      const int r = rl + reg;
      const float tot = ns[0*64+r]+ns[1*64+r]+ns[2*64+r]+ns[3*64+r];
      const float inv = 1.0f/(sqrtf(tot)+1e-6f);
      const size_t grow = (size_t)(bm + r);
      #pragma unroll
      for (int j=0;j<4;j++){
        const int c = wc*64 + j*16 + (lane&15);
        Hn[grow*256 + c] = acc[i][j][reg]*inv;
      }
    }
  }
}

// ---------------- sim GEMM + softmax + gumbel-argmax + outputs + q_inv, fused ----------------
__global__ __launch_bounds__(512) void sim_sample_kernel(
    const float* __restrict__ Hn, const unsigned short* __restrict__ packE,
    const float* __restrict__ embed, const float* __restrict__ temp,
    float* __restrict__ probs, float* __restrict__ codef,
    float* __restrict__ quant, float* __restrict__ norms,
    const float* __restrict__ Epp, const float* __restrict__ pinv_b,
    float* __restrict__ q_inv,
    uint32_t kc0, uint32_t kc1, uint32_t kp0, uint32_t kp1){
  __shared__ char smem[40960];
  f32x4 acc[2][4];
  #pragma unroll
  for (int i=0;i<2;i++)
    #pragma unroll
    for (int j=0;j<4;j++) acc[i][j] = (f32x4){0.f,0.f,0.f,0.f};
  const int bm = blockIdx.x * 64;
  mk1_gemm(Hn + (size_t)bm*256, 256, packE, 256, smem, acc);
  __syncthreads();                      // K-loop LDS reads done before epilogue aliasing

  float* redf = (float*)smem;            // [4][64]
  int*   redi = (int*)(smem+1024);       // [4][64]
  float* smax = (float*)(smem+2048);     // [64]
  float* ssum = (float*)(smem+2304);     // [64]
  float* ssel = (float*)(smem+2560);     // [64]
  int*  scode = (int*)(smem+2816);       // [64]

  const int tid = threadIdx.x, lane = tid&63, wv = tid>>6;
  const int wr = wv>>2, wc = wv&3;
  const float tv = temp[0];
  const float alpha = 1.0f/(tv*tv);
  #pragma unroll
  for (int i=0;i<2;i++)
    #pragma unroll
    for (int j=0;j<4;j++)
      #pragma unroll
      for (int reg=0;reg<4;reg++){
        const float s = acc[i][j][reg];
        const float dist = -2.0f*(alpha-1.0f)*s - 2.0f*s;
        acc[i][j][reg] = -dist;
      }
  // row max
  #pragma unroll
  for (int i=0;i<2;i++)
    #pragma unroll
    for (int reg=0;reg<4;reg++){
      float m = fmaxf(fmaxf(acc[i][0][reg], acc[i][1][reg]),
                      fmaxf(acc[i][2][reg], acc[i][3][reg]));
      #pragma unroll
      for (int o=1;o<16;o<<=1) m = fmaxf(m, __shfl_xor(m, o));
      if ((lane&15)==0) redf[wc*64 + wr*32 + i*16 + (lane>>4)*4 + reg] = m;
    }
  __syncthreads();
  if (tid < 64)
    smax[tid] = fmaxf(fmaxf(redf[0*64+tid], redf[1*64+tid]), fmaxf(redf[2*64+tid], redf[3*64+tid]));
  __syncthreads();
  // exp-sum
  #pragma unroll
  for (int i=0;i<2;i++)
    #pragma unroll
    for (int reg=0;reg<4;reg++){
      const int r = wr*32 + i*16 + (lane>>4)*4 + reg;
      const float m = smax[r];
      float p = expf(acc[i][0][reg]-m) + expf(acc[i][1][reg]-m)
              + expf(acc[i][2][reg]-m) + expf(acc[i][3][reg]-m);
      #pragma unroll
      for (int o=1;o<16;o<<=1) p += __shfl_xor(p, o);
      if ((lane&15)==0) redf[wc*64 + r] = p;
    }
  __syncthreads();
  if (tid < 64){
    ssum[tid] = redf[0*64+tid]+redf[1*64+tid]+redf[2*64+tid]+redf[3*64+tid];
    const uint32_t pb = random_bits32(kp0,kp1,(uint32_t)(bm+tid), 16384u);
    const float pf = __uint_as_float((pb>>9) | 0x3f800000u) - 1.0f;
    ssel[tid] = (pf > 0.0f) ? 1.0f : 0.0f;
  }
  __syncthreads();
  // gumbel argmax (bit-frozen comparison order)
  #pragma unroll
  for (int i=0;i<2;i++)
    #pragma unroll
    for (int reg=0;reg<4;reg++){
      const int r = wr*32 + i*16 + (lane>>4)*4 + reg;
      const uint32_t grow = (uint32_t)(bm + r);
      float zb = -1e38f; int ib = 0x7fffffff;
      #pragma unroll
      for (int j=0;j<4;j++){
        const int c = wc*64 + j*16 + (lane&15);
        const uint32_t bits = random_bits32(kc0,kc1, grow*256u + (uint32_t)c, 4194304u);
        const float f = __uint_as_float((bits>>9) | 0x3f800000u) - 1.0f;
        const float TINY = 1.17549435082228751e-38f;
        const float u = fmaxf(TINY, f + TINY);
        const float g = -logf(-logf(u));
        const float z = acc[i][j][reg] + g;
        if (z > zb || (z == zb && c < ib)){ zb = z; ib = c; }
      }
      #pragma unroll
      for (int o=1;o<16;o<<=1){
        const float zo = __shfl_xor(zb, o); const int io = __shfl_xor(ib, o);
        if (zo > zb || (zo == zb && io < ib)){ zb = zo; ib = io; }
      }
      if ((lane&15)==0){ redf[wc*64 + r] = zb; redi[wc*64 + r] = ib; }
    }
  __syncthreads();
  if (tid < 64){
    float zb = redf[0*64+tid]; int ib = redi[0*64+tid];
    #pragma unroll
    for (int w=1; w<4; w++)
      if (redf[w*64+tid] > zb || (redf[w*64+tid] == zb && redi[w*64+tid] < ib)){
        zb = redf[w*64+tid]; ib = redi[w*64+tid];
      }
    scode[tid] = ib;
  }
  __syncthreads();
  // probs/quant + ||embed[code]-h|| partials
  #pragma unroll
  for (int i=0;i<2;i++)
    #pragma unroll
    for (int reg=0;reg<4;reg++){
      const int r = wr*32 + i*16 + (lane>>4)*4 + reg;
      const size_t grow = (size_t)(bm + r);
      const float m = smax[r], sum = ssum[r], sel = ssel[r];
      const int code = scode[r];
      float p2 = 0.f;
      #pragma unroll
      for (int j=0;j<4;j++){
        const int c = wc*64 + j*16 + (lane&15);
        const float e = expf(acc[i][j][reg] - m);
        probs[grow*256 + c] = (e/sum) * sel;
        const float ev = embed[(size_t)code*256 + c];
        quant[grow*256 + c] = ev * sel;
        const float d = ev - Hn[grow*256 + c];
        p2 += d*d;
      }
      #pragma unroll
      for (int o=1;o<16;o<<=1) p2 += __shfl_xor(p2, o);
      if ((lane&15)==0) redf[wc*64 + r] = p2;
    }
  __syncthreads();
  if (tid < 64){
    norms[bm+tid] = sqrtf(redf[0*64+tid]+redf[1*64+tid]+redf[2*64+tid]+redf[3*64+tid]);
    codef[bm+tid] = (float)scode[tid] * ssel[tid];
  }
  // q_inv rows: sel ? Epp[code] : pinv_b (wave wv owns rows wv*8..wv*8+7)
  #pragma unroll
  for (int rr=0; rr<8; rr++){
    const int r = wv*8 + rr;
    const int code = scode[r];
    const float sel = ssel[r];
    const float4* s4 = (const float4*)((sel != 0.0f) ? (Epp + (size_t)code*2048) : pinv_b);
    float4* dst = (float4*)(q_inv + (size_t)(bm + r)*2048);
    #pragma unroll
    for (int q=0;q<8;q++) dst[q*64 + lane] = s4[q*64 + lane];
  }
}

// ---------------- vq_loss = mean(norms) ----------------
__global__ __launch_bounds__(256) void loss_kernel(const float* __restrict__ norms,
                                                   float* __restrict__ outp){
  const int t = threadIdx.x;
  float s = 0.f;
  for (int i=t;i<32768;i+=256) s += norms[i];
  #pragma unroll
  for (int o=32;o;o>>=1) s += __shfl_xor(s,o);
  __shared__ float wred[4];
  if ((t&63)==0) wred[t>>6]=s;
  __syncthreads();
  if (t==0) outp[0] = (wred[0]+wred[1]+wred[2]+wred[3]) * (1.0f/32768.0f);
}

// ---------------- launch ----------------
extern "C" void kernel_launch(void* const* d_in, const int* in_sizes, int n_in,
                              void* d_out, int out_size, void* d_ws, size_t ws_size,
                              hipStream_t stream){
  const float* h_in  = (const float*)d_in[0];
  const float* temp  = (const float*)d_in[1];
  const float* proj_w= (const float*)d_in[2];
  const float* proj_b= (const float*)d_in[3];
  const float* pinv_w= (const float*)d_in[4];
  const float* pinv_b= (const float*)d_in[5];
  const float* w0 = (const float*)d_in[6];
  const float* b0 = (const float*)d_in[7];
  const float* g0 = (const float*)d_in[8];
  const float* be0= (const float*)d_in[9];
  const float* wm = (const float*)d_in[10];
  const float* bm = (const float*)d_in[11];
  const float* gm = (const float*)d_in[12];
  const float* bem= (const float*)d_in[13];
  const float* wL = (const float*)d_in[14];
  const float* bL = (const float*)d_in[15];

  float* out = (float*)d_out;
  float* q_inv  = out;                  // [32768,2048]
  float* o_code = out + 67108864;       // [32768]
  float* o_quant= out + 67141632;       // [32768,256]
  float* o_probs= out + 75530240;       // [32768,256]
  float* o_loss = out + 83918848;       // [1]

  // scratch in d_ws
  float* ws = (float*)d_ws;
  float* Hn     = ws + 0;               // [32768,256]
  float* X0b    = ws + 8388608;         // [256,1024]
  float* X1b    = ws + 8650752;         // [256,1024]
  float* embed  = ws + 8912896;         // [256,256]
  float* norms  = ws + 8978432;         // [32768]
  float* Epp    = ws + 9076736;         // [256,2048]
  unsigned short* packW = (unsigned short*)(ws + 9601024);   // 64 steps x 16384 shorts
  unsigned short* packE = (unsigned short*)(ws + 10125312);  // 8 steps x 16384 shorts

  uint32_t kc0,kc1,kp0,kp1;
#if PARTITIONABLE
  threefry2x32(0u,42u, 0u,0u, kc0,kc1);
  threefry2x32(0u,42u, 0u,1u, kp0,kp1);
#else
  { uint32_t a0,b0w,a1,b1w;
    threefry2x32(0u,42u, 0u,2u, a0,b0w);
    threefry2x32(0u,42u, 1u,3u, a1,b1w);
    kc0=a0; kc1=a1; kp0=b0w; kp1=b1w; }
#endif

  // pre-split proj_w into the LDS-image pack
  pack_w_kernel<<<256,256,0,stream>>>(proj_w, packW);

  // codebook MLP -> embed + packE (f32, k-order bit-identical to prior rounds)
  cb_fc0_kernel<<<1024,256,0,stream>>>(w0, b0, X0b);
  bn_relu_kernel<<<16,256,0,stream>>>(X0b, g0, be0, X1b, 1024);
  for (int l=0;l<4;l++){
    gemm_f32<32,64,2,4><<<dim3(16,8),256,0,stream>>>(X1b, wm + (size_t)l*1048576, bm + l*1024, X0b, 256,1024,1024);
    bn_relu_kernel<<<16,256,0,stream>>>(X0b, gm + l*1024, bem + l*1024, X1b, 1024);
  }
  gemm_f32<32,64,2,4><<<dim3(4,8),256,0,stream>>>(X1b, wL, bL, X0b, 256,256,1024);
  rownorm_pack_kernel<<<256,256,0,stream>>>(X0b, embed, packE);

  // E'' = embed @ pinv_w + pinv_b (f32, tiny)
  gemm_f32<32,64,2,4><<<dim3(32,8),256,0,stream>>>(embed, pinv_w, pinv_b, Epp, 256,2048,256);

  // fused proj+normalize (512 blocks, 40KB LDS -> 2 blocks/CU)
  proj_norm_kernel<<<512,512,0,stream>>>(h_in, packW, proj_b, Hn, 2048);

  // sim + sample + all per-token outputs incl. q_inv
  sim_sample_kernel<<<512,512,0,stream>>>(Hn, packE, embed, temp,
                                          o_probs, o_code, o_quant, norms,
                                          Epp, pinv_b, q_inv,
                                          kc0,kc1,kp0,kp1);
  loss_kernel<<<1,256,0,stream>>>(norms, o_loss);
}